// Round 6
// baseline (577.497 us; speedup 1.0000x reference)
//
#include <hip/hip_runtime.h>

// LSTM anomaly detector: B=4096, T=512, I=3, H=64 (4H=256 gates)
// R8 = R3's twice-verified chassis (ROWS=16, 4 waves, 1 barrier/step) with
// the per-step critical path shortened:
//  - Decoder OFF the chain: iter t computes out[t-1] with the SAME A-frags
//    (h_{t-1}) the gate MFMAs use, as 2 independent 3-deep chains issued
//    concurrently with the 12 gate chains (rotating wave). OOF flush moves
//    to chunk-START iters (extra barrier there makes slot-63 visible).
//  - Gate preacts: three 2-deep MFMA chains per tile (same terms as R4's
//    pass: hi*Bh, lo*Bh, hi*Bl + exact-fp32 x seed) instead of 4+5-deep.
//  - x-path: fp32 VALU FMAs (R4/R7-verified), prefetched before barrier.
//  - h-split: R3/R4's trunc bit recipe, byte-for-byte.
// (Resubmission of R8 — previous round failed on infra, kernel never ran.)

#define TLEN 512
#define TCHUNK 64
#define ROWS 16

typedef float  float4_t __attribute__((ext_vector_type(4)));
typedef __bf16 bf16x8   __attribute__((ext_vector_type(8)));

__device__ __forceinline__ float fexp2(float x){ return __builtin_amdgcn_exp2f(x); }
__device__ __forceinline__ float frcp (float x){ return __builtin_amdgcn_rcpf(x); }
__device__ __forceinline__ float sigm (float x){ return frcp(1.f + fexp2(-1.44269504f*x)); }
__device__ __forceinline__ float tanh_(float x){ return 1.f - 2.f*frcp(1.f + fexp2(2.88539008f*x)); }

// setup-only RNE split (weights; cost irrelevant)
__device__ __forceinline__ void split8(const float* v, bf16x8& hi, bf16x8& lo){
  #pragma unroll
  for (int j = 0; j < 8; j++){
    __bf16 h = (__bf16)v[j];
    hi[j] = h;
    lo[j] = (__bf16)(v[j] - (float)h);
  }
}

#define MFMA(a,b,c) __builtin_amdgcn_mfma_f32_16x16x32_bf16((a),(b),(c),0,0,0)

// ---- LDS layout ----
// ushort region: h exchange, double-buffered, rows stride 72 (16B-aligned)
#define HHI 0                 // 2 buf x [16 rows][72] hi
#define HLO 2304              // 2 buf x [16 rows][72] lo
#define HS_SZ 4608
// float region:
#define XOF 0                 // [16 rows][196] fp32 raw x staging
#define XPK 3136              // [64 t][16 rows][4] packed {x0,x1,x2,0}
#define OOF 7232              // [16 rows][196] fp32 out staging
#define LF_SZ 10368

__global__ __launch_bounds__(256, 1)
void LSTMAnomalyDetector_kernel(
    const float* __restrict__ x,     const float* __restrict__ W_ih,
    const float* __restrict__ W_hh,  const float* __restrict__ b_ih,
    const float* __restrict__ b_hh,  const float* __restrict__ W_dec,
    const float* __restrict__ b_dec, float* __restrict__ out)
{
  __shared__ __align__(16) unsigned short HS[HS_SZ];
  __shared__ __align__(16) float          LF[LF_SZ];

  const int tid  = threadIdx.x;
  const int w    = tid >> 6;        // wave 0..3
  const int lane = tid & 63;
  const int q    = lane >> 4;       // quad 0..3
  const int lid  = lane & 15;
  const int b0   = blockIdx.x * ROWS;
  const int cw   = w*16 + lid;      // this lane's H-column

  // ---- resident weight fragments (B-operand: B[k=kt*32+q*8+j][n=lid]) ----
  bf16x8 Bh[4][2], Bl[4][2];  // W_hh^T hi/lo; tl = gate type (i,f,g,o)
  bf16x8 Dh[2],    Dl[2];     // decoder: W_dec^T (cols 0..2 valid)
  float  wi[4][3], bsum[4];   // fp32 x-path: W_ih row + (b_ih+b_hh)

  #pragma unroll
  for (int tl = 0; tl < 4; tl++){
    const int g = tl*64 + cw;                   // gate row (W_hh[256][64] row-major)
    #pragma unroll
    for (int kt = 0; kt < 2; kt++){
      const float* p = W_hh + g*64 + kt*32 + q*8;
      float v[8];
      #pragma unroll
      for (int j = 0; j < 8; j++) v[j] = p[j];
      split8(v, Bh[tl][kt], Bl[tl][kt]);
    }
    wi[tl][0] = W_ih[g*3+0];
    wi[tl][1] = W_ih[g*3+1];
    wi[tl][2] = W_ih[g*3+2];
    bsum[tl]  = b_ih[g] + b_hh[g];
  }
  #pragma unroll
  for (int kt = 0; kt < 2; kt++){
    float v[8] = {0.f,0.f,0.f,0.f,0.f,0.f,0.f,0.f};
    if (lid < 3){
      const float* p = W_dec + lid*64 + kt*32 + q*8;
      #pragma unroll
      for (int j = 0; j < 8; j++) v[j] = p[j];
    }
    split8(v, Dh[kt], Dl[kt]);
  }
  const float bdec = (lid < 3) ? b_dec[lid] : 0.f;

  // ---- state ----
  bf16x8 ah0 = {}, ah1 = {}, al0 = {}, al1 = {};   // h_{t-1} A-frags (hi/lo)
  float creg[4] = {0.f, 0.f, 0.f, 0.f};            // c for rows q*4+r @ col cw
  float4_t xp4[4];                                 // fp32 x-part per gate, 4 rows

  auto loadx = [&](int d){
    #pragma unroll
    for (int r = 0; r < 4; r++){
      float4_t xv = *(const float4_t*)&LF[XPK + d*64 + (q*4+r)*4];
      #pragma unroll
      for (int tl = 0; tl < 4; tl++)
        xp4[tl][r] = fmaf(wi[tl][2], xv[2],
                      fmaf(wi[tl][1], xv[1],
                        fmaf(wi[tl][0], xv[0], bsum[tl])));
    }
  };

  // ---- preload + pack x chunk 0 ----
  #pragma unroll
  for (int s = 0; s < 3; s++){
    const int f = tid + 256*s;                 // 768 float4 = 16 rows x 48
    const int row = f/48; const int off = (f%48)*4;
    float4_t v = *(const float4_t*)(x + (size_t)(b0+row)*1536 + off);
    *(float4_t*)&LF[XOF + row*196 + off] = v;
  }
  __syncthreads();
  #pragma unroll
  for (int s = 0; s < 4; s++){
    const int p = tid + 256*s;                 // p = t*16 + row, 0..1023
    const float* xr = &LF[XOF + (p & 15)*196 + (p >> 4)*3];
    float4_t v = {xr[0], xr[1], xr[2], 0.f};
    *(float4_t*)&LF[XPK + p*4] = v;
  }
  __syncthreads();
  loadx(0);

  for (int t = 0; t < TLEN; ++t){
    const int dt = t & (TCHUNK-1);
    const int hb = (t & 1) * 1152;

    // --- MFMA phase: 12 gate chains (depth 2) + decoder chains ride along ---
    float4_t g4[4];
    #pragma unroll
    for (int tl = 0; tl < 4; tl++){
      float4_t c1 = {0.f,0.f,0.f,0.f};
      float4_t c2 = {0.f,0.f,0.f,0.f};
      float4_t c3 = xp4[tl];
      c1 = MFMA(ah0, Bh[tl][0], c1);
      c1 = MFMA(ah1, Bh[tl][1], c1);
      c2 = MFMA(al0, Bh[tl][0], c2);
      c2 = MFMA(al1, Bh[tl][1], c2);
      c3 = MFMA(ah0, Bl[tl][0], c3);
      c3 = MFMA(ah1, Bl[tl][1], c3);
      g4[tl] = (c1 + c2) + c3;
    }

    // decoder for step t-1 (A-frags still hold h_{t-1}); rotating wave
    if (t > 0 && w == ((t-1) & 3)){
      float4_t dA = {0.f,0.f,0.f,0.f};
      float4_t dB = {0.f,0.f,0.f,0.f};
      dA = MFMA(ah0, Dh[0], dA);
      dA = MFMA(ah1, Dh[1], dA);
      dA = MFMA(al0, Dh[0], dA);
      dB = MFMA(al1, Dh[1], dB);
      dB = MFMA(ah0, Dl[0], dB);
      dB = MFMA(ah1, Dl[1], dB);
      dA += dB;
      if (lid < 3){
        const int dto = (t-1) & (TCHUNK-1);
        #pragma unroll
        for (int r = 0; r < 4; r++)
          LF[OOF + (q*4+r)*196 + dto*3 + lid] = dA[r] + bdec;
      }
    }

    // chunk-start flush: OOF now holds out[t-64 .. t-1]
    if (t > 0 && dt == 0){
      __syncthreads();                         // slot-63 OOF write visible
      const int t0 = t - TCHUNK;
      #pragma unroll
      for (int s = 0; s < 3; s++){
        const int f = tid + 256*s;
        const int row = f/48; const int off = (f%48)*4;
        float4_t v = *(const float4_t*)&LF[OOF + row*196 + off];
        *(float4_t*)(out + (size_t)(b0+row)*1536 + t0*3 + off) = v;
      }
    }

    // lane-local activations + c/h update; trunc h-split (R3/R4 recipe)
    #pragma unroll
    for (int r = 0; r < 4; r++){
      const float ig = sigm (g4[0][r]);
      const float fg = sigm (g4[1][r]);
      const float gg = tanh_(g4[2][r]);
      const float og = sigm (g4[3][r]);
      creg[r] = fg*creg[r] + ig*gg;
      const float h = og * tanh_(creg[r]);
      const unsigned u  = __float_as_uint(h);
      const float    lf = h - __uint_as_float(u & 0xFFFF0000u);   // exact
      const int m = q*4 + r;
      HS[HHI + hb + m*72 + cw] = (unsigned short)(u >> 16);
      HS[HLO + hb + m*72 + cw] = (unsigned short)(__float_as_uint(lf) >> 16);
    }

    // prefetch next step's x-part BEFORE the barrier
    if (dt != TCHUNK-1){
      loadx(dt+1);
    } else if (t + 1 < TLEN){
      // stage + pack next x chunk (XPK idle: last read was iter t-1)
      #pragma unroll
      for (int s = 0; s < 3; s++){
        const int f = tid + 256*s;
        const int row = f/48; const int off = (f%48)*4;
        float4_t v = *(const float4_t*)(x + (size_t)(b0+row)*1536 + (t+1)*3 + off);
        *(float4_t*)&LF[XOF + row*196 + off] = v;
      }
      __syncthreads();
      #pragma unroll
      for (int s = 0; s < 4; s++){
        const int p = tid + 256*s;
        const float* xr = &LF[XOF + (p & 15)*196 + (p >> 4)*3];
        float4_t v = {xr[0], xr[1], xr[2], 0.f};
        *(float4_t*)&LF[XPK + p*4] = v;
      }
    }

    __syncthreads();   // the ONE main barrier: h_t + (staged XPK) ready

    // rebuild A-frags: 4 raw ds_read_b128, zero VALU
    {
      const unsigned short* ph = &HS[HHI + hb + lid*72 + q*8];
      const unsigned short* pl = &HS[HLO + hb + lid*72 + q*8];
      ah0 = *(const bf16x8*)&ph[0];
      ah1 = *(const bf16x8*)&ph[32];
      al0 = *(const bf16x8*)&pl[0];
      al1 = *(const bf16x8*)&pl[32];
    }
    if (dt == TCHUNK-1 && t + 1 < TLEN) loadx(0);
  }

  // ---- epilogue: decoder for h_511 -> OOF slot 63, then final flush ----
  if (w == 3){                                  // (512-1)&3
    float4_t dA = {0.f,0.f,0.f,0.f};
    float4_t dB = {0.f,0.f,0.f,0.f};
    dA = MFMA(ah0, Dh[0], dA);
    dA = MFMA(ah1, Dh[1], dA);
    dA = MFMA(al0, Dh[0], dA);
    dB = MFMA(al1, Dh[1], dB);
    dB = MFMA(ah0, Dl[0], dB);
    dB = MFMA(ah1, Dl[1], dB);
    dA += dB;
    if (lid < 3){
      #pragma unroll
      for (int r = 0; r < 4; r++)
        LF[OOF + (q*4+r)*196 + 63*3 + lid] = dA[r] + bdec;
    }
  }
  __syncthreads();
  {
    const int t0 = TLEN - TCHUNK;
    #pragma unroll
    for (int s = 0; s < 3; s++){
      const int f = tid + 256*s;
      const int row = f/48; const int off = (f%48)*4;
      float4_t v = *(const float4_t*)&LF[OOF + row*196 + off];
      *(float4_t*)(out + (size_t)(b0+row)*1536 + t0*3 + off) = v;
    }
  }
}

extern "C" void kernel_launch(void* const* d_in, const int* in_sizes, int n_in,
                              void* d_out, int out_size, void* d_ws, size_t ws_size,
                              hipStream_t stream)
{
  const float* x     = (const float*)d_in[0];
  const float* W_ih  = (const float*)d_in[1];
  const float* W_hh  = (const float*)d_in[2];
  const float* b_ih  = (const float*)d_in[3];
  const float* b_hh  = (const float*)d_in[4];
  const float* W_dec = (const float*)d_in[5];
  const float* b_dec = (const float*)d_in[6];
  float* out = (float*)d_out;

  const int B = in_sizes[0] / (TLEN * 3);   // 4096
  const int blocks = B / ROWS;              // 256
  hipLaunchKernelGGL(LSTMAnomalyDetector_kernel, dim3(blocks), dim3(256), 0, stream,
                     x, W_ih, W_hh, b_ih, b_hh, W_dec, b_dec, out);
}

// Round 7
// 524.530 us; speedup vs baseline: 1.1010x; 1.1010x over previous
//
#include <hip/hip_runtime.h>

// LSTM anomaly detector: B=4096, T=512, I=3, H=64 (4H=256 gates)
// R10 = R3's twice-verified chassis + phase overlap:
//  - x-path exact fp32 FMA (R4/R7/R8-passed): kills the 12 mostly-zero
//    x-MFMAs -> matrix phase 612->408 cyc/step.
//  - Gate-interleaved activations: i-sigm issued after tile0, f after tile1,
//    g after tile2, o after tile3 -> VALU trans execute under the matrix
//    pipe of the next tile. Per-cell arithmetic identical to R4's pass
//    (accA 4-chain + xp-seeded accB 2-chain, trunc h-split).
//  - Everything else R3 verbatim: ROWS=16, 4 waves, 1 barrier/step,
//    decoder on wave 0 after rebuild (slack-absorbed), chunk machinery.

#define TLEN 512
#define TCHUNK 64
#define ROWS 16

typedef float  float4_t __attribute__((ext_vector_type(4)));
typedef __bf16 bf16x8   __attribute__((ext_vector_type(8)));

__device__ __forceinline__ float fexp2(float x){ return __builtin_amdgcn_exp2f(x); }
__device__ __forceinline__ float frcp (float x){ return __builtin_amdgcn_rcpf(x); }
__device__ __forceinline__ float sigm (float x){ return frcp(1.f + fexp2(-1.44269504f*x)); }
__device__ __forceinline__ float tanh_(float x){ return 1.f - 2.f*frcp(1.f + fexp2(2.88539008f*x)); }

// setup-only RNE split (weights; cost irrelevant)
__device__ __forceinline__ void split8(const float* v, bf16x8& hi, bf16x8& lo){
  #pragma unroll
  for (int j = 0; j < 8; j++){
    __bf16 h = (__bf16)v[j];
    hi[j] = h;
    lo[j] = (__bf16)(v[j] - (float)h);
  }
}

#define MFMA(a,b,c) __builtin_amdgcn_mfma_f32_16x16x32_bf16((a),(b),(c),0,0,0)

// ---- LDS layout ----
// ushort region: h exchange, double-buffered, rows stride 72 (16B-aligned)
#define HHI 0                 // 2 buf x [16 rows][72] hi
#define HLO 2304              // 2 buf x [16 rows][72] lo
#define HS_SZ 4608
// float region:
#define XOF 0                 // [16 rows][196] fp32 raw x staging
#define XPK 3136              // [64 t][16 rows][4] packed {x0,x1,x2,0}
#define OOF 7232              // [16 rows][196] fp32 out staging
#define LF_SZ 10368

__global__ __launch_bounds__(256, 1)
void LSTMAnomalyDetector_kernel(
    const float* __restrict__ x,     const float* __restrict__ W_ih,
    const float* __restrict__ W_hh,  const float* __restrict__ b_ih,
    const float* __restrict__ b_hh,  const float* __restrict__ W_dec,
    const float* __restrict__ b_dec, float* __restrict__ out)
{
  __shared__ __align__(16) unsigned short HS[HS_SZ];
  __shared__ __align__(16) float          LF[LF_SZ];

  const int tid  = threadIdx.x;
  const int w    = tid >> 6;        // wave 0..3
  const int lane = tid & 63;
  const int q    = lane >> 4;       // quad 0..3
  const int lid  = lane & 15;
  const int b0   = blockIdx.x * ROWS;
  const int cw   = w*16 + lid;      // this lane's H-column

  // ---- resident weight fragments (B-operand: B[k=kt*32+q*8+j][n=lid]) ----
  bf16x8 Bh[4][2], Bl[4][2];  // W_hh^T hi/lo; tl = gate type (i,f,g,o)
  bf16x8 Dh[2],    Dl[2];     // decoder: W_dec^T (cols 0..2 valid)
  float  wi[4][3], bsum[4];   // fp32 x-path: W_ih row + (b_ih+b_hh)

  #pragma unroll
  for (int tl = 0; tl < 4; tl++){
    const int g = tl*64 + cw;                   // gate row (W_hh[256][64] row-major)
    #pragma unroll
    for (int kt = 0; kt < 2; kt++){
      const float* p = W_hh + g*64 + kt*32 + q*8;
      float v[8];
      #pragma unroll
      for (int j = 0; j < 8; j++) v[j] = p[j];
      split8(v, Bh[tl][kt], Bl[tl][kt]);
    }
    wi[tl][0] = W_ih[g*3+0];
    wi[tl][1] = W_ih[g*3+1];
    wi[tl][2] = W_ih[g*3+2];
    bsum[tl]  = b_ih[g] + b_hh[g];
  }
  #pragma unroll
  for (int kt = 0; kt < 2; kt++){
    float v[8] = {0.f,0.f,0.f,0.f,0.f,0.f,0.f,0.f};
    if (lid < 3){
      const float* p = W_dec + lid*64 + kt*32 + q*8;
      #pragma unroll
      for (int j = 0; j < 8; j++) v[j] = p[j];
    }
    split8(v, Dh[kt], Dl[kt]);
  }
  const float bdec = (lid < 3) ? b_dec[lid] : 0.f;

  // ---- state ----
  bf16x8 ah0 = {}, ah1 = {}, al0 = {}, al1 = {};   // h_{t-1} A-frags (hi/lo)
  float creg[4] = {0.f, 0.f, 0.f, 0.f};            // c for rows q*4+r @ col cw
  float4_t xp4[4];                                 // fp32 x-part per gate, 4 rows

  auto loadx = [&](int d){
    #pragma unroll
    for (int r = 0; r < 4; r++){
      float4_t xv = *(const float4_t*)&LF[XPK + d*64 + (q*4+r)*4];
      #pragma unroll
      for (int tl = 0; tl < 4; tl++)
        xp4[tl][r] = fmaf(wi[tl][2], xv[2],
                      fmaf(wi[tl][1], xv[1],
                        fmaf(wi[tl][0], xv[0], bsum[tl])));
    }
  };

  // ---- preload + pack x chunk 0 ----
  #pragma unroll
  for (int s = 0; s < 3; s++){
    const int f = tid + 256*s;                 // 768 float4 = 16 rows x 48
    const int row = f/48; const int off = (f%48)*4;
    float4_t v = *(const float4_t*)(x + (size_t)(b0+row)*1536 + off);
    *(float4_t*)&LF[XOF + row*196 + off] = v;
  }
  __syncthreads();
  #pragma unroll
  for (int s = 0; s < 4; s++){
    const int p = tid + 256*s;                 // p = t*16 + row, 0..1023
    const float* xr = &LF[XOF + (p & 15)*196 + (p >> 4)*3];
    float4_t v = {xr[0], xr[1], xr[2], 0.f};
    *(float4_t*)&LF[XPK + p*4] = v;
  }
  __syncthreads();
  loadx(0);

  for (int t = 0; t < TLEN; ++t){
    const int dt = t & (TCHUNK-1);
    const int hb = (t & 1) * 1152;

    // ---- tile 0 (i-gate) ----
    float4_t accA = {0.f,0.f,0.f,0.f};
    accA = MFMA(ah0, Bh[0][0], accA);
    accA = MFMA(ah1, Bh[0][1], accA);
    accA = MFMA(al0, Bh[0][0], accA);
    accA = MFMA(al1, Bh[0][1], accA);
    float4_t accB = xp4[0];
    accB = MFMA(ah0, Bl[0][0], accB);
    accB = MFMA(ah1, Bl[0][1], accB);
    float4_t g0 = accA + accB;
    // i-activations issue on VALU while tile 1 runs on the matrix pipe
    float4_t ig;
    #pragma unroll
    for (int r = 0; r < 4; r++) ig[r] = sigm(g0[r]);

    // ---- tile 1 (f-gate) ----
    accA = (float4_t){0.f,0.f,0.f,0.f};
    accA = MFMA(ah0, Bh[1][0], accA);
    accA = MFMA(ah1, Bh[1][1], accA);
    accA = MFMA(al0, Bh[1][0], accA);
    accA = MFMA(al1, Bh[1][1], accA);
    accB = xp4[1];
    accB = MFMA(ah0, Bl[1][0], accB);
    accB = MFMA(ah1, Bl[1][1], accB);
    float4_t g1 = accA + accB;
    float4_t fg;
    #pragma unroll
    for (int r = 0; r < 4; r++) fg[r] = sigm(g1[r]);

    // ---- tile 2 (g-gate) ----
    accA = (float4_t){0.f,0.f,0.f,0.f};
    accA = MFMA(ah0, Bh[2][0], accA);
    accA = MFMA(ah1, Bh[2][1], accA);
    accA = MFMA(al0, Bh[2][0], accA);
    accA = MFMA(al1, Bh[2][1], accA);
    accB = xp4[2];
    accB = MFMA(ah0, Bl[2][0], accB);
    accB = MFMA(ah1, Bl[2][1], accB);
    float4_t g2 = accA + accB;
    float4_t gg;
    #pragma unroll
    for (int r = 0; r < 4; r++) gg[r] = tanh_(g2[r]);

    // ---- tile 3 (o-gate) ----
    accA = (float4_t){0.f,0.f,0.f,0.f};
    accA = MFMA(ah0, Bh[3][0], accA);
    accA = MFMA(ah1, Bh[3][1], accA);
    accA = MFMA(al0, Bh[3][0], accA);
    accA = MFMA(al1, Bh[3][1], accA);
    accB = xp4[3];
    accB = MFMA(ah0, Bl[3][0], accB);
    accB = MFMA(ah1, Bl[3][1], accB);
    float4_t g3 = accA + accB;

    // ---- tail: o-sigm, c/h update, trunc split, h writes (R3 recipe) ----
    #pragma unroll
    for (int r = 0; r < 4; r++){
      const float og = sigm(g3[r]);
      creg[r] = fg[r]*creg[r] + ig[r]*gg[r];
      const float h = og * tanh_(creg[r]);
      const unsigned u  = __float_as_uint(h);
      const float    lf = h - __uint_as_float(u & 0xFFFF0000u);   // exact
      const int m = q*4 + r;
      HS[HHI + hb + m*72 + cw] = (unsigned short)(u >> 16);
      HS[HLO + hb + m*72 + cw] = (unsigned short)(__float_as_uint(lf) >> 16);
    }

    // prefetch next step's x-part BEFORE the barrier
    if (dt != TCHUNK-1) loadx(dt+1);

    __syncthreads();   // the ONE barrier per step

    // rebuild A-frags: 4 raw ds_read_b128, zero VALU
    {
      const unsigned short* ph = &HS[HHI + hb + lid*72 + q*8];
      const unsigned short* pl = &HS[HLO + hb + lid*72 + q*8];
      ah0 = *(const bf16x8*)&ph[0];
      ah1 = *(const bf16x8*)&ph[32];
      al0 = *(const bf16x8*)&pl[0];
      al1 = *(const bf16x8*)&pl[32];
    }

    // decoder on wave 0 (R3 style; slack-absorbed): out_t -> OOF slot dt
    if (w == 0){
      float4_t d = {0.f,0.f,0.f,0.f};
      d = MFMA(ah0, Dh[0], d);
      d = MFMA(ah1, Dh[1], d);
      d = MFMA(al0, Dh[0], d);
      d = MFMA(al1, Dh[1], d);
      d = MFMA(ah0, Dl[0], d);
      d = MFMA(ah1, Dl[1], d);
      if (lid < 3){
        #pragma unroll
        for (int r = 0; r < 4; r++)
          LF[OOF + (q*4+r)*196 + dt*3 + lid] = d[r] + bdec;
      }
    }

    // chunk boundary: flush out, stage+pack next x chunk
    if (dt == TCHUNK-1){
      __syncthreads();
      const int t0 = t - (TCHUNK-1);
      #pragma unroll
      for (int s = 0; s < 3; s++){
        const int f = tid + 256*s;
        const int row = f/48; const int off = (f%48)*4;
        float4_t v = *(const float4_t*)&LF[OOF + row*196 + off];
        *(float4_t*)(out + (size_t)(b0+row)*1536 + t0*3 + off) = v;
      }
      if (t + 1 < TLEN){
        #pragma unroll
        for (int s = 0; s < 3; s++){
          const int f = tid + 256*s;
          const int row = f/48; const int off = (f%48)*4;
          float4_t v = *(const float4_t*)(x + (size_t)(b0+row)*1536 + (t+1)*3 + off);
          *(float4_t*)&LF[XOF + row*196 + off] = v;
        }
        __syncthreads();
        #pragma unroll
        for (int s = 0; s < 4; s++){
          const int p = tid + 256*s;
          const float* xr = &LF[XOF + (p & 15)*196 + (p >> 4)*3];
          float4_t v = {xr[0], xr[1], xr[2], 0.f};
          *(float4_t*)&LF[XPK + p*4] = v;
        }
      }
      __syncthreads();
      if (t + 1 < TLEN) loadx(0);
    }
  }
}

extern "C" void kernel_launch(void* const* d_in, const int* in_sizes, int n_in,
                              void* d_out, int out_size, void* d_ws, size_t ws_size,
                              hipStream_t stream)
{
  const float* x     = (const float*)d_in[0];
  const float* W_ih  = (const float*)d_in[1];
  const float* W_hh  = (const float*)d_in[2];
  const float* b_ih  = (const float*)d_in[3];
  const float* b_hh  = (const float*)d_in[4];
  const float* W_dec = (const float*)d_in[5];
  const float* b_dec = (const float*)d_in[6];
  float* out = (float*)d_out;

  const int B = in_sizes[0] / (TLEN * 3);   // 4096
  const int blocks = B / ROWS;              // 256
  hipLaunchKernelGGL(LSTMAnomalyDetector_kernel, dim3(blocks), dim3(256), 0, stream,
                     x, W_ih, W_hh, b_ih, b_hh, W_dec, b_dec, out);
}

// Round 8
// 485.309 us; speedup vs baseline: 1.1900x; 1.0808x over previous
//
#include <hip/hip_runtime.h>

// LSTM anomaly detector: B=4096, T=512, I=3, H=64 (4H=256 gates)
// R11 = R10 chassis with the recurrence moved to fp16 MFMA:
//  - W_hh as fp16 PAIR: Bh = fp16(W); Bl = fp16((W - Bh) * 2048) (scaled into
//    the normal range to dodge denormal flush); gate = c1 + c2/2048.
//    Effective W precision ~2^-22 (better than old bf16-pair ~2^-17, which
//    drove the measured systematic 2^-10 absmax).
//  - h as SINGLE RNE fp16 (rel 2^-12, unbiased vs old trunc-split bias):
//    4 MFMA/tile (16/wave), 4 ds_write_b16 + 2 ds_read_b128 per step,
//    no split VALU.
//  - Everything else R10 verbatim: fp32 x-path (exact), gate-interleaved
//    activations, 1 barrier/step, decoder on wave 0 post-rebuild (4 MFMA),
//    chunk staging machinery.

#define TLEN 512
#define TCHUNK 64
#define ROWS 16

typedef float    float4_t __attribute__((ext_vector_type(4)));
typedef _Float16 halfx8   __attribute__((ext_vector_type(8)));

#define INV2048 4.8828125e-4f

__device__ __forceinline__ float fexp2(float x){ return __builtin_amdgcn_exp2f(x); }
__device__ __forceinline__ float frcp (float x){ return __builtin_amdgcn_rcpf(x); }
__device__ __forceinline__ float sigm (float x){ return frcp(1.f + fexp2(-1.44269504f*x)); }
__device__ __forceinline__ float tanh_(float x){ return 1.f - 2.f*frcp(1.f + fexp2(2.88539008f*x)); }

__device__ __forceinline__ unsigned short hbits(_Float16 h){
  union { _Float16 h; unsigned short u; } x; x.h = h; return x.u;
}

// setup-only fp16 pair split (lo-plane scaled by 2048 to stay normal)
__device__ __forceinline__ void split8h(const float* v, halfx8& hi, halfx8& lo){
  #pragma unroll
  for (int j = 0; j < 8; j++){
    _Float16 h = (_Float16)v[j];
    hi[j] = h;
    lo[j] = (_Float16)((v[j] - (float)h) * 2048.0f);
  }
}

#define MFMA(a,b,c) __builtin_amdgcn_mfma_f32_16x16x32_f16((a),(b),(c),0,0,0)

// ---- LDS layout ----
// ushort region: h exchange (fp16, single plane), double-buffered, stride 72
#define HHI 0                 // 2 buf x [16 rows][72]
#define HS_SZ 2304
// float region:
#define XOF 0                 // [16 rows][196] fp32 raw x staging
#define XPK 3136              // [64 t][16 rows][4] packed {x0,x1,x2,0}
#define OOF 7232              // [16 rows][196] fp32 out staging
#define LF_SZ 10368

__global__ __launch_bounds__(256, 1)
void LSTMAnomalyDetector_kernel(
    const float* __restrict__ x,     const float* __restrict__ W_ih,
    const float* __restrict__ W_hh,  const float* __restrict__ b_ih,
    const float* __restrict__ b_hh,  const float* __restrict__ W_dec,
    const float* __restrict__ b_dec, float* __restrict__ out)
{
  __shared__ __align__(16) unsigned short HS[HS_SZ];
  __shared__ __align__(16) float          LF[LF_SZ];

  const int tid  = threadIdx.x;
  const int w    = tid >> 6;        // wave 0..3
  const int lane = tid & 63;
  const int q    = lane >> 4;       // quad 0..3
  const int lid  = lane & 15;
  const int b0   = blockIdx.x * ROWS;
  const int cw   = w*16 + lid;      // this lane's H-column

  // ---- resident weight fragments (B-operand: B[k=kt*32+q*8+j][n=lid]) ----
  halfx8 Bh[4][2], Bl[4][2];  // W_hh^T fp16 pair; tl = gate type (i,f,g,o)
  halfx8 Dh[2],    Dl[2];     // decoder: W_dec^T fp16 pair (cols 0..2 valid)
  float  wi[4][3], bsum[4];   // fp32 x-path: W_ih row + (b_ih+b_hh)

  #pragma unroll
  for (int tl = 0; tl < 4; tl++){
    const int g = tl*64 + cw;                   // gate row (W_hh[256][64] row-major)
    #pragma unroll
    for (int kt = 0; kt < 2; kt++){
      const float* p = W_hh + g*64 + kt*32 + q*8;
      float v[8];
      #pragma unroll
      for (int j = 0; j < 8; j++) v[j] = p[j];
      split8h(v, Bh[tl][kt], Bl[tl][kt]);
    }
    wi[tl][0] = W_ih[g*3+0];
    wi[tl][1] = W_ih[g*3+1];
    wi[tl][2] = W_ih[g*3+2];
    bsum[tl]  = b_ih[g] + b_hh[g];
  }
  #pragma unroll
  for (int kt = 0; kt < 2; kt++){
    float v[8] = {0.f,0.f,0.f,0.f,0.f,0.f,0.f,0.f};
    if (lid < 3){
      const float* p = W_dec + lid*64 + kt*32 + q*8;
      #pragma unroll
      for (int j = 0; j < 8; j++) v[j] = p[j];
    }
    split8h(v, Dh[kt], Dl[kt]);
  }
  const float bdec = (lid < 3) ? b_dec[lid] : 0.f;

  // ---- state ----
  halfx8 ah0 = {}, ah1 = {};                  // h_{t-1} A-frags (fp16), h_{-1}=0
  float creg[4] = {0.f, 0.f, 0.f, 0.f};       // c for rows q*4+r @ col cw
  float4_t xp4[4];                            // fp32 x-part per gate, 4 rows

  auto loadx = [&](int d){
    #pragma unroll
    for (int r = 0; r < 4; r++){
      float4_t xv = *(const float4_t*)&LF[XPK + d*64 + (q*4+r)*4];
      #pragma unroll
      for (int tl = 0; tl < 4; tl++)
        xp4[tl][r] = fmaf(wi[tl][2], xv[2],
                      fmaf(wi[tl][1], xv[1],
                        fmaf(wi[tl][0], xv[0], bsum[tl])));
    }
  };

  // ---- preload + pack x chunk 0 ----
  #pragma unroll
  for (int s = 0; s < 3; s++){
    const int f = tid + 256*s;                 // 768 float4 = 16 rows x 48
    const int row = f/48; const int off = (f%48)*4;
    float4_t v = *(const float4_t*)(x + (size_t)(b0+row)*1536 + off);
    *(float4_t*)&LF[XOF + row*196 + off] = v;
  }
  __syncthreads();
  #pragma unroll
  for (int s = 0; s < 4; s++){
    const int p = tid + 256*s;                 // p = t*16 + row, 0..1023
    const float* xr = &LF[XOF + (p & 15)*196 + (p >> 4)*3];
    float4_t v = {xr[0], xr[1], xr[2], 0.f};
    *(float4_t*)&LF[XPK + p*4] = v;
  }
  __syncthreads();
  loadx(0);

  for (int t = 0; t < TLEN; ++t){
    const int dt = t & (TCHUNK-1);
    const int hb = (t & 1) * 1152;

    // ---- tile 0 (i-gate): c1 = xp-seed + h*Whi (K=64); c2 = h*Wlo*2048 ----
    float4_t c1 = xp4[0];
    c1 = MFMA(ah0, Bh[0][0], c1);
    c1 = MFMA(ah1, Bh[0][1], c1);
    float4_t c2 = {0.f,0.f,0.f,0.f};
    c2 = MFMA(ah0, Bl[0][0], c2);
    c2 = MFMA(ah1, Bl[0][1], c2);
    float4_t g0;
    #pragma unroll
    for (int r = 0; r < 4; r++) g0[r] = fmaf(c2[r], INV2048, c1[r]);
    float4_t ig;
    #pragma unroll
    for (int r = 0; r < 4; r++) ig[r] = sigm(g0[r]);

    // ---- tile 1 (f-gate) ----
    c1 = xp4[1];
    c1 = MFMA(ah0, Bh[1][0], c1);
    c1 = MFMA(ah1, Bh[1][1], c1);
    c2 = (float4_t){0.f,0.f,0.f,0.f};
    c2 = MFMA(ah0, Bl[1][0], c2);
    c2 = MFMA(ah1, Bl[1][1], c2);
    float4_t g1;
    #pragma unroll
    for (int r = 0; r < 4; r++) g1[r] = fmaf(c2[r], INV2048, c1[r]);
    float4_t fg;
    #pragma unroll
    for (int r = 0; r < 4; r++) fg[r] = sigm(g1[r]);

    // ---- tile 2 (g-gate) ----
    c1 = xp4[2];
    c1 = MFMA(ah0, Bh[2][0], c1);
    c1 = MFMA(ah1, Bh[2][1], c1);
    c2 = (float4_t){0.f,0.f,0.f,0.f};
    c2 = MFMA(ah0, Bl[2][0], c2);
    c2 = MFMA(ah1, Bl[2][1], c2);
    float4_t g2;
    #pragma unroll
    for (int r = 0; r < 4; r++) g2[r] = fmaf(c2[r], INV2048, c1[r]);
    float4_t gg;
    #pragma unroll
    for (int r = 0; r < 4; r++) gg[r] = tanh_(g2[r]);

    // ---- tile 3 (o-gate) ----
    c1 = xp4[3];
    c1 = MFMA(ah0, Bh[3][0], c1);
    c1 = MFMA(ah1, Bh[3][1], c1);
    c2 = (float4_t){0.f,0.f,0.f,0.f};
    c2 = MFMA(ah0, Bl[3][0], c2);
    c2 = MFMA(ah1, Bl[3][1], c2);
    float4_t g3;
    #pragma unroll
    for (int r = 0; r < 4; r++) g3[r] = fmaf(c2[r], INV2048, c1[r]);

    // ---- tail: o-sigm, c/h update, fp16 cvt, h writes ----
    #pragma unroll
    for (int r = 0; r < 4; r++){
      const float og = sigm(g3[r]);
      creg[r] = fg[r]*creg[r] + ig[r]*gg[r];
      const float h = og * tanh_(creg[r]);
      const _Float16 h16 = (_Float16)h;        // RNE, unbiased
      const int m = q*4 + r;
      HS[HHI + hb + m*72 + cw] = hbits(h16);
    }

    // prefetch next step's x-part BEFORE the barrier
    if (dt != TCHUNK-1) loadx(dt+1);

    __syncthreads();   // the ONE barrier per step

    // rebuild A-frags: 2 raw ds_read_b128, zero VALU
    {
      const unsigned short* ph = &HS[HHI + hb + lid*72 + q*8];
      ah0 = *(const halfx8*)&ph[0];
      ah1 = *(const halfx8*)&ph[32];
    }

    // decoder on wave 0: out_t = h_t @ W_dec^T + b_dec -> OOF slot dt
    if (w == 0){
      float4_t d1 = {0.f,0.f,0.f,0.f};
      d1 = MFMA(ah0, Dh[0], d1);
      d1 = MFMA(ah1, Dh[1], d1);
      float4_t d2 = {0.f,0.f,0.f,0.f};
      d2 = MFMA(ah0, Dl[0], d2);
      d2 = MFMA(ah1, Dl[1], d2);
      if (lid < 3){
        #pragma unroll
        for (int r = 0; r < 4; r++)
          LF[OOF + (q*4+r)*196 + dt*3 + lid] = fmaf(d2[r], INV2048, d1[r]) + bdec;
      }
    }

    // chunk boundary: flush out, stage+pack next x chunk
    if (dt == TCHUNK-1){
      __syncthreads();
      const int t0 = t - (TCHUNK-1);
      #pragma unroll
      for (int s = 0; s < 3; s++){
        const int f = tid + 256*s;
        const int row = f/48; const int off = (f%48)*4;
        float4_t v = *(const float4_t*)&LF[OOF + row*196 + off];
        *(float4_t*)(out + (size_t)(b0+row)*1536 + t0*3 + off) = v;
      }
      if (t + 1 < TLEN){
        #pragma unroll
        for (int s = 0; s < 3; s++){
          const int f = tid + 256*s;
          const int row = f/48; const int off = (f%48)*4;
          float4_t v = *(const float4_t*)(x + (size_t)(b0+row)*1536 + (t+1)*3 + off);
          *(float4_t*)&LF[XOF + row*196 + off] = v;
        }
        __syncthreads();
        #pragma unroll
        for (int s = 0; s < 4; s++){
          const int p = tid + 256*s;
          const float* xr = &LF[XOF + (p & 15)*196 + (p >> 4)*3];
          float4_t v = {xr[0], xr[1], xr[2], 0.f};
          *(float4_t*)&LF[XPK + p*4] = v;
        }
      }
      __syncthreads();
      if (t + 1 < TLEN) loadx(0);
    }
  }
}

extern "C" void kernel_launch(void* const* d_in, const int* in_sizes, int n_in,
                              void* d_out, int out_size, void* d_ws, size_t ws_size,
                              hipStream_t stream)
{
  const float* x     = (const float*)d_in[0];
  const float* W_ih  = (const float*)d_in[1];
  const float* W_hh  = (const float*)d_in[2];
  const float* b_ih  = (const float*)d_in[3];
  const float* b_hh  = (const float*)d_in[4];
  const float* W_dec = (const float*)d_in[5];
  const float* b_dec = (const float*)d_in[6];
  float* out = (float*)d_out;

  const int B = in_sizes[0] / (TLEN * 3);   // 4096
  const int blocks = B / ROWS;              // 256
  hipLaunchKernelGGL(LSTMAnomalyDetector_kernel, dim3(blocks), dim3(256), 0, stream,
                     x, W_ih, W_hh, b_ih, b_hh, W_dec, b_dec, out);
}